// Round 9
// baseline (121.167 us; speedup 1.0000x reference)
//
#include <hip/hip_runtime.h>

#define N_NODES 50000
#define N_EDGES 400000
#define F_INP 5
#define HD 256          // HEADS*DIM = 2*128
#define BN_EPS 1e-5f

typedef short v8s __attribute__((ext_vector_type(8)));
typedef float v4f __attribute__((ext_vector_type(4)));
typedef unsigned v4u __attribute__((ext_vector_type(4)));

// ---- workspace layout (float offsets) ----
#define OFF_HBN  0          // N*8  (padded rows: 5 used + 3 pad)
#define OFF_ACC  400000     // N*16 (den0,S0[5],den1,S1[5],cnt,pad3)
#define OFF_BPK  1200000    // 16 tiles * 64 lanes * 2 dwords (k_edge B)
#define OFF_WF   1202048    // 128 rows * 16 floats: Wfuse[0..12], sc, sh, pad
#define OFF_W2P  1204096    // 128*8 padded W2

// float -> bf16 RNE
__device__ __forceinline__ unsigned short f2bf(float f) {
    unsigned u = __float_as_uint(f);
    return (unsigned short)((u + 0x7FFFu + ((u >> 16) & 1u)) >> 16);
}
__device__ __forceinline__ unsigned pk2(float a, float b) {
    return (unsigned)f2bf(a) | ((unsigned)f2bf(b) << 16);
}

// W_cat[k][c]: k 0..4 = Wl, 5..9 = Wr, 10 = We, 11 = bl+br
__device__ __forceinline__ float wcat(int k, int c, const float* Wl, const float* Wr,
                                      const float* We, const float* bl, const float* br) {
    if (k < 5)   return Wl[k * HD + c];
    if (k < 10)  return Wr[(k - 5) * HD + c];
    if (k == 10) return We[c];
    return bl[c] + br[c];
}

// prep: zero acc + BN1 -> hbn8 + pack k_edge B fragments (unchanged from R7 pass)
__global__ void k_prep(const float* __restrict__ h, const float* __restrict__ g1,
                       const float* __restrict__ be1, const float* __restrict__ rm1,
                       const float* __restrict__ rv1,
                       const float* __restrict__ Wl, const float* __restrict__ bl,
                       const float* __restrict__ Wr, const float* __restrict__ br,
                       const float* __restrict__ We, const float* __restrict__ att,
                       float* __restrict__ hbn8, float* __restrict__ acc,
                       unsigned* __restrict__ Bpk) {
    int i = blockIdx.x * blockDim.x + threadIdx.x;
    if (i < N_NODES * 16) acc[i] = 0.f;
    if (i < N_NODES * 8) {
        int f = i & 7, n = i >> 3;
        float v = 0.f;
        if (f < F_INP) {
            float x = h[n * F_INP + f];
            v = (x - rm1[f]) * rsqrtf(rv1[f] + BN_EPS) * g1[f] + be1[f];
        }
        hbn8[i] = v;
    }
    if (i < 1024) {  // B fragment pack: tile t, lane l
        int t = i >> 6, l = i & 63;
        int g = l >> 4, c = t * 16 + (l & 15);
        unsigned d0 = 0, d1 = 0;
        if (g < 3) {
            int kb = 4 * g;
            d0 = pk2(wcat(kb + 0, c, Wl, Wr, We, bl, br),
                     wcat(kb + 1, c, Wl, Wr, We, bl, br));
            d1 = pk2(wcat(kb + 2, c, Wl, Wr, We, bl, br),
                     wcat(kb + 3, c, Wl, Wr, We, bl, br));
        }
        Bpk[(t * 64 + l) * 2 + 0] = d0;
        Bpk[(t * 64 + l) * 2 + 1] = d1;
    }
}

// pack2 (fp32): Wf[c][0..12] = (Wx @ W1)[.,c] (+ b1 folded into k=12 row),
// Wf[c][13] = BN2 scale, Wf[c][14] = BN2 shift; W2p[c][0..4] = W2 row.
// Wx rows: 0=bl[0:128], 1=bl[128:256], 2..6=Wl[f][0:128], 7..11=Wl[f][128:256],
//          12=bias_gat
__global__ void k_pack2(const float* __restrict__ Wl, const float* __restrict__ bl,
                        const float* __restrict__ bias_gat,
                        const float* __restrict__ W1, const float* __restrict__ b1,
                        const float* __restrict__ g2, const float* __restrict__ be2,
                        const float* __restrict__ rm2, const float* __restrict__ rv2,
                        const float* __restrict__ W2,
                        float* __restrict__ Wf, float* __restrict__ W2p) {
    int c = blockIdx.x * blockDim.x + threadIdx.x;
    if (c >= 128) return;
#pragma unroll
    for (int k = 0; k < 13; ++k) {
        const float* base = (k == 0) ? bl
                          : (k == 1) ? bl + 128
                          : (k < 7)  ? Wl + (k - 2) * HD
                          : (k < 12) ? Wl + (k - 7) * HD + 128
                                     : bias_gat;
        float sum = 0.f;
        for (int d = 0; d < 128; ++d) sum += base[d] * W1[d * 128 + c];
        if (k == 12) sum += b1[c];
        Wf[c * 16 + k] = sum;
    }
    float sc = g2[c] * rsqrtf(rv2[c] + BN_EPS);
    Wf[c * 16 + 13] = sc;
    Wf[c * 16 + 14] = be2[c] - rm2[c] * sc;
    Wf[c * 16 + 15] = 0.f;
#pragma unroll
    for (int f = 0; f < 8; ++f)
        W2p[c * 8 + f] = (f < 5) ? W2[c * 5 + f] : 0.f;
}

// MFMA edge kernel, fully LDS-free (validated R6/R7): 16 edges per wave-iteration.
__launch_bounds__(256)
__global__ void k_edge(const float* __restrict__ hbn8, const int* __restrict__ ei,
                       const float* __restrict__ ew, const unsigned* __restrict__ Bpk,
                       const float* __restrict__ att, float* __restrict__ acc) {
    int lane = threadIdx.x & 63;
    int wv = threadIdx.x >> 6;
    int g = lane >> 4, e16 = lane & 15;

    v8s B[16];
    float AT[16];
#pragma unroll
    for (int t = 0; t < 16; ++t) {
        unsigned d0 = Bpk[(t * 64 + lane) * 2 + 0];
        unsigned d1 = Bpk[(t * 64 + lane) * 2 + 1];
        v4u u = {d0, d1, 0u, 0u};
        B[t] = __builtin_bit_cast(v8s, u);
        AT[t] = att[t * 16 + e16];
    }

    int wid = blockIdx.x * 4 + wv;
    int nw = gridDim.x * 4;
    const int NT = N_EDGES / 16;

    int q13 = lane / 13;
    int j13 = lane - q13 * 13;
    bool sc_act = lane < 52;
    int kk = (j13 < 6) ? j13 - 1 : j13 - 7;
    int kc = min(max(kk, 0), 4);

    float x0 = 0, x1 = 0, x2 = 0, x3 = 0, x4 = 0,
          x5 = 0, x6 = 0, x7 = 0, x8 = 0, x9 = 0, x10 = 0;
    int dst_reg = 0;
    if (wid < NT && lane < 16) {
        int e = wid * 16 + lane;
        int src = ei[e];
        dst_reg = ei[N_EDGES + e];
        x10 = ew[e];
        float4 s4 = *(const float4*)&hbn8[src * 8];
        x0 = s4.x; x1 = s4.y; x2 = s4.z; x3 = s4.w;
        x4 = hbn8[src * 8 + 4];
        float4 d4 = *(const float4*)&hbn8[dst_reg * 8];
        x5 = d4.x; x6 = d4.y; x7 = d4.z; x8 = d4.w;
        x9 = hbn8[dst_reg * 8 + 4];
    }

    for (int tile = wid; tile < NT; tile += nw) {
        float b0 = __shfl(x0, e16), b1 = __shfl(x1, e16), b2 = __shfl(x2, e16),
              b3 = __shfl(x3, e16), b4 = __shfl(x4, e16), b5 = __shfl(x5, e16),
              b6 = __shfl(x6, e16), b7 = __shfl(x7, e16), b8 = __shfl(x8, e16),
              b9 = __shfl(x9, e16), b10 = __shfl(x10, e16);
        int dst_b = __shfl(dst_reg, e16);

        float a0 = (g == 0) ? b0 : (g == 1) ? b4 : b8;
        float a1 = (g == 0) ? b1 : (g == 1) ? b5 : b9;
        float a2 = (g == 0) ? b2 : (g == 1) ? b6 : b10;
        float a3 = (g == 0) ? b3 : (g == 1) ? b7 : 1.0f;
        unsigned ua0 = (g < 3) ? pk2(a0, a1) : 0u;
        unsigned ua1 = (g < 3) ? pk2(a2, a3) : 0u;
        v4u uav = {ua0, ua1, 0u, 0u};
        v8s A = __builtin_bit_cast(v8s, uav);

        int tn = tile + nw;
        if (tn < NT && lane < 16) {
            int e = tn * 16 + lane;
            int src = ei[e];
            dst_reg = ei[N_EDGES + e];
            x10 = ew[e];
            float4 s4 = *(const float4*)&hbn8[src * 8];
            x0 = s4.x; x1 = s4.y; x2 = s4.z; x3 = s4.w;
            x4 = hbn8[src * 8 + 4];
            float4 d4 = *(const float4*)&hbn8[dst_reg * 8];
            x5 = d4.x; x6 = d4.y; x7 = d4.z; x8 = d4.w;
            x9 = hbn8[dst_reg * 8 + 4];
        }

        float p00 = 0.f, p01 = 0.f, p02 = 0.f, p03 = 0.f;
        float p10 = 0.f, p11 = 0.f, p12 = 0.f, p13v = 0.f;
        v4f zero = {0.f, 0.f, 0.f, 0.f};
#pragma unroll
        for (int t = 0; t < 8; ++t) {
            v4f c = __builtin_amdgcn_mfma_f32_16x16x32_bf16(A, B[t], zero, 0, 0, 0);
            p00 += AT[t] * fmaf(0.66666667f, fabsf(c[0]), c[0]);
            p01 += AT[t] * fmaf(0.66666667f, fabsf(c[1]), c[1]);
            p02 += AT[t] * fmaf(0.66666667f, fabsf(c[2]), c[2]);
            p03 += AT[t] * fmaf(0.66666667f, fabsf(c[3]), c[3]);
        }
#pragma unroll
        for (int t = 8; t < 16; ++t) {
            v4f c = __builtin_amdgcn_mfma_f32_16x16x32_bf16(A, B[t], zero, 0, 0, 0);
            p10 += AT[t] * fmaf(0.66666667f, fabsf(c[0]), c[0]);
            p11 += AT[t] * fmaf(0.66666667f, fabsf(c[1]), c[1]);
            p12 += AT[t] * fmaf(0.66666667f, fabsf(c[2]), c[2]);
            p13v += AT[t] * fmaf(0.66666667f, fabsf(c[3]), c[3]);
        }
#pragma unroll
        for (int m = 1; m <= 8; m <<= 1) {
            p00 += __shfl_xor(p00, m); p01 += __shfl_xor(p01, m);
            p02 += __shfl_xor(p02, m); p03 += __shfl_xor(p03, m);
            p10 += __shfl_xor(p10, m); p11 += __shfl_xor(p11, m);
            p12 += __shfl_xor(p12, m); p13v += __shfl_xor(p13v, m);
        }
        float e00 = __expf(0.6f * p00), e01 = __expf(0.6f * p01);
        float e02 = __expf(0.6f * p02), e03 = __expf(0.6f * p03);
        float e10 = __expf(0.6f * p10), e11 = __expf(0.6f * p11);
        float e12 = __expf(0.6f * p12), e13 = __expf(0.6f * p13v);
        float tA0 = (lane & 1) ? e01 : e00;
        float tA1 = (lane & 1) ? e03 : e02;
        float exA = (lane & 2) ? tA1 : tA0;
        float tB0 = (lane & 1) ? e11 : e10;
        float tB1 = (lane & 1) ? e13 : e12;
        float exB = (lane & 2) ? tB1 : tB0;

        if (sc_act) {
#pragma unroll
            for (int it = 0; it < 4; ++it) {
                int es = it * 4 + q13;
                float h0 = __shfl(b0, es), h1 = __shfl(b1, es), h2 = __shfl(b2, es),
                      h3 = __shfl(b3, es), h4 = __shfl(b4, es);
                int de = __shfl(dst_b, es);
                float xh0 = __shfl(exA, it * 16 + q13);
                float xh1 = __shfl(exB, it * 16 + q13);
                float hsel = h0;
                hsel = (kc == 1) ? h1 : hsel;
                hsel = (kc == 2) ? h2 : hsel;
                hsel = (kc == 3) ? h3 : hsel;
                hsel = (kc == 4) ? h4 : hsel;
                float base = (j13 < 6) ? xh0 : xh1;
                float v = base * hsel;
                v = (j13 == 0) ? xh0 : v;
                v = (j13 == 6) ? xh1 : v;
                v = (j13 == 12) ? 1.0f : v;
                atomicAdd(&acc[de * 16 + j13], v);
            }
        }
    }
}

// MLP, all-fp32 VALU (no re-quantization of atomic-accumulated values):
// one thread per node; the 128-channel loop streams wave-uniform Wf rows
// (scalarized to s_load_dwordx16) against per-lane M[13] registers.
__launch_bounds__(256)
__global__ void k_mlp(const float* __restrict__ acc, const float* __restrict__ Wf,
                      const float* __restrict__ W2p, const float* __restrict__ b2,
                      float* __restrict__ out) {
    int n = blockIdx.x * blockDim.x + threadIdx.x;
    if (n >= N_NODES) return;
    const float* ar = acc + (size_t)n * 16;
    float4 A0 = *(const float4*)(ar + 0);   // den0 S00 S01 S02
    float4 A1 = *(const float4*)(ar + 4);   // S03 S04 den1 S10
    float4 A2 = *(const float4*)(ar + 8);   // S11 S12 S13 S14
    float cnt = ar[12];
    float r0 = 1.f / (A0.x + 1e-16f);
    float r1 = 1.f / (A1.z + 1e-16f);
    float scale = 0.5f / fmaxf(cnt, 1.f);
    float s0 = scale * r0, s1 = scale * r1;
    // M[k] matching Wf row order (k0=bl_h0, k1=bl_h1, k2..6=Wl_h0, k7..11=Wl_h1, k12=1)
    float m0 = A0.x * s0, m1 = A1.z * s1;
    float m2 = A0.y * s0, m3 = A0.z * s0, m4 = A0.w * s0, m5 = A1.x * s0, m6 = A1.y * s0;
    float m7 = A1.w * s1, m8 = A2.x * s1, m9 = A2.y * s1, m10 = A2.z * s1, m11 = A2.w * s1;

    float o0 = 0.f, o1 = 0.f, o2 = 0.f, o3 = 0.f, o4 = 0.f;
#pragma unroll 4
    for (int c = 0; c < 128; ++c) {
        const float* wr = &Wf[c * 16];
        float a = wr[12];                    // k12 row (M12 = 1)
        a += m0 * wr[0] + m1 * wr[1] + m2 * wr[2] + m3 * wr[3];
        a += m4 * wr[4] + m5 * wr[5] + m6 * wr[6] + m7 * wr[7];
        a += m8 * wr[8] + m9 * wr[9] + m10 * wr[10] + m11 * wr[11];
        a = fmaf(a, wr[13], wr[14]);         // BN2 folded
        a = fmaxf(a, 0.01f * a);             // lrelu 0.01
        const float* w2 = &W2p[c * 8];
        o0 = fmaf(a, w2[0], o0);
        o1 = fmaf(a, w2[1], o1);
        o2 = fmaf(a, w2[2], o2);
        o3 = fmaf(a, w2[3], o3);
        o4 = fmaf(a, w2[4], o4);
    }
    float* op = out + (size_t)n * 5;
    op[0] = o0 + b2[0];
    op[1] = o1 + b2[1];
    op[2] = o2 + b2[2];
    op[3] = o3 + b2[3];
    op[4] = o4 + b2[4];
}

extern "C" void kernel_launch(void* const* d_in, const int* in_sizes, int n_in,
                              void* d_out, int out_size, void* d_ws, size_t ws_size,
                              hipStream_t stream) {
    const float* h    = (const float*)d_in[0];
    const int*   ei   = (const int*)d_in[1];
    const float* ew   = (const float*)d_in[2];
    const float* g1   = (const float*)d_in[3];
    const float* be1  = (const float*)d_in[4];
    const float* rm1  = (const float*)d_in[5];
    const float* rv1  = (const float*)d_in[6];
    const float* Wl   = (const float*)d_in[7];
    const float* bl   = (const float*)d_in[8];
    const float* Wr   = (const float*)d_in[9];
    const float* br   = (const float*)d_in[10];
    const float* We   = (const float*)d_in[11];
    const float* att  = (const float*)d_in[12];
    const float* bias_gat = (const float*)d_in[13];
    const float* W1   = (const float*)d_in[14];
    const float* b1   = (const float*)d_in[15];
    const float* g2   = (const float*)d_in[16];
    const float* be2  = (const float*)d_in[17];
    const float* rm2  = (const float*)d_in[18];
    const float* rv2  = (const float*)d_in[19];
    const float* W2   = (const float*)d_in[20];
    const float* b2   = (const float*)d_in[21];

    float* ws  = (float*)d_ws;
    float* hbn = ws + OFF_HBN;
    float* acc = ws + OFF_ACC;
    unsigned* Bpk = (unsigned*)(ws + OFF_BPK);
    float* Wf  = ws + OFF_WF;
    float* W2p = ws + OFF_W2P;

    k_prep<<<(N_NODES * 16 + 255) / 256, 256, 0, stream>>>(
        h, g1, be1, rm1, rv1, Wl, bl, Wr, br, We, att, hbn, acc, Bpk);
    k_pack2<<<1, 128, 0, stream>>>(Wl, bl, bias_gat, W1, b1, g2, be2, rm2, rv2, W2,
                                   Wf, W2p);
    k_edge<<<1024, 256, 0, stream>>>(hbn, ei, ew, Bpk, att, acc);
    k_mlp<<<(N_NODES + 255) / 256, 256, 0, stream>>>(acc, Wf, W2p, b2, (float*)d_out);
}

// Round 10
// 87.453 us; speedup vs baseline: 1.3855x; 1.3855x over previous
//
#include <hip/hip_runtime.h>

#define N_NODES 50000
#define N_EDGES 400000
#define F_INP 5
#define HD 256          // HEADS*DIM = 2*128
#define BN_EPS 1e-5f

typedef short v8s __attribute__((ext_vector_type(8)));
typedef float v4f __attribute__((ext_vector_type(4)));
typedef unsigned v4u __attribute__((ext_vector_type(4)));

// ---- workspace layout (float offsets) ----
#define OFF_HBN  0          // N*8  (padded rows: 5 used + 3 pad)
#define OFF_ACC  400000     // N*16 (den0,S0[5],den1,S1[5],cnt,pad3)
#define OFF_BPK  1200000    // 16 tiles * 64 lanes * 2 dwords (k_edge B)
#define OFF_WF   1202048    // 128 rows * 16 floats: Wfuse[0..12], sc, sh, pad
#define OFF_W2P  1204096    // 128*8 padded W2

// float -> bf16 RNE
__device__ __forceinline__ unsigned short f2bf(float f) {
    unsigned u = __float_as_uint(f);
    return (unsigned short)((u + 0x7FFFu + ((u >> 16) & 1u)) >> 16);
}
__device__ __forceinline__ unsigned pk2(float a, float b) {
    return (unsigned)f2bf(a) | ((unsigned)f2bf(b) << 16);
}

// W_cat[k][c]: k 0..4 = Wl, 5..9 = Wr, 10 = We, 11 = bl+br
__device__ __forceinline__ float wcat(int k, int c, const float* Wl, const float* Wr,
                                      const float* We, const float* bl, const float* br) {
    if (k < 5)   return Wl[k * HD + c];
    if (k < 10)  return Wr[(k - 5) * HD + c];
    if (k == 10) return We[c];
    return bl[c] + br[c];
}

// prep: zero acc + BN1 -> hbn8 + pack k_edge B fragments (validated R7/R9)
__global__ void k_prep(const float* __restrict__ h, const float* __restrict__ g1,
                       const float* __restrict__ be1, const float* __restrict__ rm1,
                       const float* __restrict__ rv1,
                       const float* __restrict__ Wl, const float* __restrict__ bl,
                       const float* __restrict__ Wr, const float* __restrict__ br,
                       const float* __restrict__ We, const float* __restrict__ att,
                       float* __restrict__ hbn8, float* __restrict__ acc,
                       unsigned* __restrict__ Bpk) {
    int i = blockIdx.x * blockDim.x + threadIdx.x;
    if (i < N_NODES * 16) acc[i] = 0.f;
    if (i < N_NODES * 8) {
        int f = i & 7, n = i >> 3;
        float v = 0.f;
        if (f < F_INP) {
            float x = h[n * F_INP + f];
            v = (x - rm1[f]) * rsqrtf(rv1[f] + BN_EPS) * g1[f] + be1[f];
        }
        hbn8[i] = v;
    }
    if (i < 1024) {  // B fragment pack: tile t, lane l
        int t = i >> 6, l = i & 63;
        int g = l >> 4, c = t * 16 + (l & 15);
        unsigned d0 = 0, d1 = 0;
        if (g < 3) {
            int kb = 4 * g;
            d0 = pk2(wcat(kb + 0, c, Wl, Wr, We, bl, br),
                     wcat(kb + 1, c, Wl, Wr, We, bl, br));
            d1 = pk2(wcat(kb + 2, c, Wl, Wr, We, bl, br),
                     wcat(kb + 3, c, Wl, Wr, We, bl, br));
        }
        Bpk[(t * 64 + l) * 2 + 0] = d0;
        Bpk[(t * 64 + l) * 2 + 1] = d1;
    }
}

// pack2 (fp32, parallel): block k (0..12) x thread c (0..127).
// Wf[c][k] = (Wx @ W1)[k,c] (+ b1 folded into k=12); Wf[c][13/14] = BN2 sc/sh.
// Wx rows: 0=bl[0:128], 1=bl[128:256], 2..6=Wl[f][0:128], 7..11=Wl[f][128:256],
//          12=bias_gat
__global__ void k_pack2(const float* __restrict__ Wl, const float* __restrict__ bl,
                        const float* __restrict__ bias_gat,
                        const float* __restrict__ W1, const float* __restrict__ b1,
                        const float* __restrict__ g2, const float* __restrict__ be2,
                        const float* __restrict__ rm2, const float* __restrict__ rv2,
                        const float* __restrict__ W2,
                        float* __restrict__ Wf, float* __restrict__ W2p) {
    int k = blockIdx.x;
    int c = threadIdx.x;
    const float* base = (k == 0) ? bl
                      : (k == 1) ? bl + 128
                      : (k < 7)  ? Wl + (k - 2) * HD
                      : (k < 12) ? Wl + (k - 7) * HD + 128
                                 : bias_gat;
    float sum = 0.f;
#pragma unroll 8
    for (int d = 0; d < 128; ++d) sum += base[d] * W1[d * 128 + c];
    if (k == 12) sum += b1[c];
    Wf[c * 16 + k] = sum;
    if (k == 0) {
        float sc = g2[c] * rsqrtf(rv2[c] + BN_EPS);
        Wf[c * 16 + 13] = sc;
        Wf[c * 16 + 14] = be2[c] - rm2[c] * sc;
        Wf[c * 16 + 15] = 0.f;
#pragma unroll
        for (int f = 0; f < 8; ++f)
            W2p[c * 8 + f] = (f < 5) ? W2[c * 5 + f] : 0.f;
    }
}

// MFMA edge kernel, fully LDS-free (validated R6/R7/R9): 16 edges per wave-iter.
__launch_bounds__(256)
__global__ void k_edge(const float* __restrict__ hbn8, const int* __restrict__ ei,
                       const float* __restrict__ ew, const unsigned* __restrict__ Bpk,
                       const float* __restrict__ att, float* __restrict__ acc) {
    int lane = threadIdx.x & 63;
    int wv = threadIdx.x >> 6;
    int g = lane >> 4, e16 = lane & 15;

    v8s B[16];
    float AT[16];
#pragma unroll
    for (int t = 0; t < 16; ++t) {
        unsigned d0 = Bpk[(t * 64 + lane) * 2 + 0];
        unsigned d1 = Bpk[(t * 64 + lane) * 2 + 1];
        v4u u = {d0, d1, 0u, 0u};
        B[t] = __builtin_bit_cast(v8s, u);
        AT[t] = att[t * 16 + e16];
    }

    int wid = blockIdx.x * 4 + wv;
    int nw = gridDim.x * 4;
    const int NT = N_EDGES / 16;

    int q13 = lane / 13;
    int j13 = lane - q13 * 13;
    bool sc_act = lane < 52;
    int kk = (j13 < 6) ? j13 - 1 : j13 - 7;
    int kc = min(max(kk, 0), 4);

    float x0 = 0, x1 = 0, x2 = 0, x3 = 0, x4 = 0,
          x5 = 0, x6 = 0, x7 = 0, x8 = 0, x9 = 0, x10 = 0;
    int dst_reg = 0;
    if (wid < NT && lane < 16) {
        int e = wid * 16 + lane;
        int src = ei[e];
        dst_reg = ei[N_EDGES + e];
        x10 = ew[e];
        float4 s4 = *(const float4*)&hbn8[src * 8];
        x0 = s4.x; x1 = s4.y; x2 = s4.z; x3 = s4.w;
        x4 = hbn8[src * 8 + 4];
        float4 d4 = *(const float4*)&hbn8[dst_reg * 8];
        x5 = d4.x; x6 = d4.y; x7 = d4.z; x8 = d4.w;
        x9 = hbn8[dst_reg * 8 + 4];
    }

    for (int tile = wid; tile < NT; tile += nw) {
        float b0 = __shfl(x0, e16), b1 = __shfl(x1, e16), b2 = __shfl(x2, e16),
              b3 = __shfl(x3, e16), b4 = __shfl(x4, e16), b5 = __shfl(x5, e16),
              b6 = __shfl(x6, e16), b7 = __shfl(x7, e16), b8 = __shfl(x8, e16),
              b9 = __shfl(x9, e16), b10 = __shfl(x10, e16);
        int dst_b = __shfl(dst_reg, e16);

        float a0 = (g == 0) ? b0 : (g == 1) ? b4 : b8;
        float a1 = (g == 0) ? b1 : (g == 1) ? b5 : b9;
        float a2 = (g == 0) ? b2 : (g == 1) ? b6 : b10;
        float a3 = (g == 0) ? b3 : (g == 1) ? b7 : 1.0f;
        unsigned ua0 = (g < 3) ? pk2(a0, a1) : 0u;
        unsigned ua1 = (g < 3) ? pk2(a2, a3) : 0u;
        v4u uav = {ua0, ua1, 0u, 0u};
        v8s A = __builtin_bit_cast(v8s, uav);

        int tn = tile + nw;
        if (tn < NT && lane < 16) {
            int e = tn * 16 + lane;
            int src = ei[e];
            dst_reg = ei[N_EDGES + e];
            x10 = ew[e];
            float4 s4 = *(const float4*)&hbn8[src * 8];
            x0 = s4.x; x1 = s4.y; x2 = s4.z; x3 = s4.w;
            x4 = hbn8[src * 8 + 4];
            float4 d4 = *(const float4*)&hbn8[dst_reg * 8];
            x5 = d4.x; x6 = d4.y; x7 = d4.z; x8 = d4.w;
            x9 = hbn8[dst_reg * 8 + 4];
        }

        float p00 = 0.f, p01 = 0.f, p02 = 0.f, p03 = 0.f;
        float p10 = 0.f, p11 = 0.f, p12 = 0.f, p13v = 0.f;
        v4f zero = {0.f, 0.f, 0.f, 0.f};
#pragma unroll
        for (int t = 0; t < 8; ++t) {
            v4f c = __builtin_amdgcn_mfma_f32_16x16x32_bf16(A, B[t], zero, 0, 0, 0);
            p00 += AT[t] * fmaf(0.66666667f, fabsf(c[0]), c[0]);
            p01 += AT[t] * fmaf(0.66666667f, fabsf(c[1]), c[1]);
            p02 += AT[t] * fmaf(0.66666667f, fabsf(c[2]), c[2]);
            p03 += AT[t] * fmaf(0.66666667f, fabsf(c[3]), c[3]);
        }
#pragma unroll
        for (int t = 8; t < 16; ++t) {
            v4f c = __builtin_amdgcn_mfma_f32_16x16x32_bf16(A, B[t], zero, 0, 0, 0);
            p10 += AT[t] * fmaf(0.66666667f, fabsf(c[0]), c[0]);
            p11 += AT[t] * fmaf(0.66666667f, fabsf(c[1]), c[1]);
            p12 += AT[t] * fmaf(0.66666667f, fabsf(c[2]), c[2]);
            p13v += AT[t] * fmaf(0.66666667f, fabsf(c[3]), c[3]);
        }
#pragma unroll
        for (int m = 1; m <= 8; m <<= 1) {
            p00 += __shfl_xor(p00, m); p01 += __shfl_xor(p01, m);
            p02 += __shfl_xor(p02, m); p03 += __shfl_xor(p03, m);
            p10 += __shfl_xor(p10, m); p11 += __shfl_xor(p11, m);
            p12 += __shfl_xor(p12, m); p13v += __shfl_xor(p13v, m);
        }
        float e00 = __expf(0.6f * p00), e01 = __expf(0.6f * p01);
        float e02 = __expf(0.6f * p02), e03 = __expf(0.6f * p03);
        float e10 = __expf(0.6f * p10), e11 = __expf(0.6f * p11);
        float e12 = __expf(0.6f * p12), e13 = __expf(0.6f * p13v);
        float tA0 = (lane & 1) ? e01 : e00;
        float tA1 = (lane & 1) ? e03 : e02;
        float exA = (lane & 2) ? tA1 : tA0;
        float tB0 = (lane & 1) ? e11 : e10;
        float tB1 = (lane & 1) ? e13 : e12;
        float exB = (lane & 2) ? tB1 : tB0;

        if (sc_act) {
#pragma unroll
            for (int it = 0; it < 4; ++it) {
                int es = it * 4 + q13;
                float h0 = __shfl(b0, es), h1 = __shfl(b1, es), h2 = __shfl(b2, es),
                      h3 = __shfl(b3, es), h4 = __shfl(b4, es);
                int de = __shfl(dst_b, es);
                float xh0 = __shfl(exA, it * 16 + q13);
                float xh1 = __shfl(exB, it * 16 + q13);
                float hsel = h0;
                hsel = (kc == 1) ? h1 : hsel;
                hsel = (kc == 2) ? h2 : hsel;
                hsel = (kc == 3) ? h3 : hsel;
                hsel = (kc == 4) ? h4 : hsel;
                float base = (j13 < 6) ? xh0 : xh1;
                float v = base * hsel;
                v = (j13 == 0) ? xh0 : v;
                v = (j13 == 6) ? xh1 : v;
                v = (j13 == 12) ? 1.0f : v;
                atomicAdd(&acc[de * 16 + j13], v);
            }
        }
    }
}

// MLP, all-fp32 VALU (validated R9): one thread per node; 128-channel loop
// streams wave-uniform Wf rows against per-lane M[13] registers.
__launch_bounds__(256)
__global__ void k_mlp(const float* __restrict__ acc, const float* __restrict__ Wf,
                      const float* __restrict__ W2p, const float* __restrict__ b2,
                      float* __restrict__ out) {
    int n = blockIdx.x * blockDim.x + threadIdx.x;
    if (n >= N_NODES) return;
    const float* ar = acc + (size_t)n * 16;
    float4 A0 = *(const float4*)(ar + 0);   // den0 S00 S01 S02
    float4 A1 = *(const float4*)(ar + 4);   // S03 S04 den1 S10
    float4 A2 = *(const float4*)(ar + 8);   // S11 S12 S13 S14
    float cnt = ar[12];
    float r0 = 1.f / (A0.x + 1e-16f);
    float r1 = 1.f / (A1.z + 1e-16f);
    float scale = 0.5f / fmaxf(cnt, 1.f);
    float s0 = scale * r0, s1 = scale * r1;
    float m0 = A0.x * s0, m1 = A1.z * s1;
    float m2 = A0.y * s0, m3 = A0.z * s0, m4 = A0.w * s0, m5 = A1.x * s0, m6 = A1.y * s0;
    float m7 = A1.w * s1, m8 = A2.x * s1, m9 = A2.y * s1, m10 = A2.z * s1, m11 = A2.w * s1;

    float o0 = 0.f, o1 = 0.f, o2 = 0.f, o3 = 0.f, o4 = 0.f;
#pragma unroll 4
    for (int c = 0; c < 128; ++c) {
        const float* wr = &Wf[c * 16];
        float a = wr[12];                    // k12 row (M12 = 1)
        a += m0 * wr[0] + m1 * wr[1] + m2 * wr[2] + m3 * wr[3];
        a += m4 * wr[4] + m5 * wr[5] + m6 * wr[6] + m7 * wr[7];
        a += m8 * wr[8] + m9 * wr[9] + m10 * wr[10] + m11 * wr[11];
        a = fmaf(a, wr[13], wr[14]);         // BN2 folded
        a = fmaxf(a, 0.01f * a);             // lrelu 0.01
        const float* w2 = &W2p[c * 8];
        o0 = fmaf(a, w2[0], o0);
        o1 = fmaf(a, w2[1], o1);
        o2 = fmaf(a, w2[2], o2);
        o3 = fmaf(a, w2[3], o3);
        o4 = fmaf(a, w2[4], o4);
    }
    float* op = out + (size_t)n * 5;
    op[0] = o0 + b2[0];
    op[1] = o1 + b2[1];
    op[2] = o2 + b2[2];
    op[3] = o3 + b2[3];
    op[4] = o4 + b2[4];
}

extern "C" void kernel_launch(void* const* d_in, const int* in_sizes, int n_in,
                              void* d_out, int out_size, void* d_ws, size_t ws_size,
                              hipStream_t stream) {
    const float* h    = (const float*)d_in[0];
    const int*   ei   = (const int*)d_in[1];
    const float* ew   = (const float*)d_in[2];
    const float* g1   = (const float*)d_in[3];
    const float* be1  = (const float*)d_in[4];
    const float* rm1  = (const float*)d_in[5];
    const float* rv1  = (const float*)d_in[6];
    const float* Wl   = (const float*)d_in[7];
    const float* bl   = (const float*)d_in[8];
    const float* Wr   = (const float*)d_in[9];
    const float* br   = (const float*)d_in[10];
    const float* We   = (const float*)d_in[11];
    const float* att  = (const float*)d_in[12];
    const float* bias_gat = (const float*)d_in[13];
    const float* W1   = (const float*)d_in[14];
    const float* b1   = (const float*)d_in[15];
    const float* g2   = (const float*)d_in[16];
    const float* be2  = (const float*)d_in[17];
    const float* rm2  = (const float*)d_in[18];
    const float* rv2  = (const float*)d_in[19];
    const float* W2   = (const float*)d_in[20];
    const float* b2   = (const float*)d_in[21];

    float* ws  = (float*)d_ws;
    float* hbn = ws + OFF_HBN;
    float* acc = ws + OFF_ACC;
    unsigned* Bpk = (unsigned*)(ws + OFF_BPK);
    float* Wf  = ws + OFF_WF;
    float* W2p = ws + OFF_W2P;

    k_prep<<<(N_NODES * 16 + 255) / 256, 256, 0, stream>>>(
        h, g1, be1, rm1, rv1, Wl, bl, Wr, br, We, att, hbn, acc, Bpk);
    k_pack2<<<13, 128, 0, stream>>>(Wl, bl, bias_gat, W1, b1, g2, be2, rm2, rv2, W2,
                                    Wf, W2p);
    k_edge<<<1024, 256, 0, stream>>>(hbn, ei, ew, Bpk, att, acc);
    k_mlp<<<(N_NODES + 255) / 256, 256, 0, stream>>>(acc, Wf, W2p, b2, (float*)d_out);
}